// Round 14
// baseline (391.937 us; speedup 1.0000x reference)
//
#include <hip/hip_runtime.h>
#include <math.h>

// LSTM: I=5, H=64, L=3, O=1, B=1024, T=256, fp32 in/out.
// Round-17: barrier-free decoupled pipeline (LDS progress flags + 4-slot ring).
// r16 POST-MORTEM: stagger HURT (203->236us). Doubling barriers (258->514)
// cost ~33us -> s_barrier round ~310cy; the barrier re-syncs all 12 waves so
// the intended phase skew never survives. r15's stall = barrier + lockstep
// skew (all waves contend for the same pipe phase simultaneously).
// THIS ROUND: remove the global barrier. True deps of wg_g step t:
//   (a) own 4 waves >= t-1 (h_own(t-1) complete)
//   (b) wg_{g-1} >= t     (h_below(t) complete)        [wg>0]
//   (c) wg_{g+1} >= t-3   (slot t&3 old content h(t-4) fully consumed) [wg<2]
// Mechanism: wflag[3][4] monotonic per-wave step counters in LDS; each wave
// after h-write does lgkmcnt(0) then (lane0) flag=t. Consumers spin-poll
// (volatile b32 reads, ~100cy vs 310cy barrier). h ring deepened 2->4 slots
// (slot=t&3) so drift<=3 is overwrite-safe. Deadlock-free: every wait is on
// a strictly-past (t,g) event (DAG); flags monotonic. 100k-spin bail ->
// a protocol bug shows as garbage absmax, not a hang.
// Waves now self-stagger -> the 3 layer groups naturally interleave MFMA /
// trans on each SIMD (m114 co-issue), absorbing the skew the barrier forced.
// Kept from r15: native __expf, cvt_pk publish, exec-masked frag loads,
// hi-only h + fp32 h2f sidecar, row-scatter combine=1j, NB=256/TBr=4, bias
// as C-operand, rcp-merged i*g, fused imm-offset LDS (ring offsets are
// compile-time constants via 4x unroll), persistent frags, setprio.
// Layouts (r8 hw-verified): C/D col=lane&15,row=(lane>>4)*4+reg;
// A row=lane&15, k=(lane>>4)*8+j.
// DO NOT raise launch_bounds min-waves (r5: VGPR cap -> 4.3GB scratch).

typedef __attribute__((ext_vector_type(8))) short bf16x8;
typedef __attribute__((ext_vector_type(4))) float f32x4;

constexpr int Hh  = 64;
constexpr int Tt  = 256;
constexpr int In  = 5;
constexpr int TBr = 4;     // REAL batch rows per block (tile rows 0,4,8,12)
constexpr int NB  = 256;   // blocks (NB*TBr = 1024 = B)
constexpr int NT  = 768;   // threads (12 waves)

// LDS geometry (bytes): 4-slot ring, immediate-offset addressable.
constexpr int RB_ = 144;    // row stride (72 shorts, bank-spread pad)
constexpr int LB  = 2304;   // layer stride (16 rows * 144)
constexpr int PB  = 8192;   // ring-slot stride (6912 used, pow2 pad)
constexpr int NS  = 4;      // ring slots (covers drift <= 3)

__device__ __forceinline__ float tanhc(float x) {
    // tanh(x) = 2*sigmoid(2x) - 1; saturates correctly, NaN-free
    return fmaf(2.0f, __builtin_amdgcn_rcpf(1.0f + __expf(-2.0f * x)), -1.0f);
}

// fp32 -> bf16 round-to-nearest-even (weight load path only, not hot)
__device__ __forceinline__ short f2bf_rne(float f) {
    union { float f; unsigned u; } v; v.f = f;
    unsigned r = (v.u + 0x7fffu + ((v.u >> 16) & 1u)) >> 16;
    return (short)r;
}
// fp32 -> (hi,lo) bf16 pair via truncation; hi+lo ~= f to ~2^-16 rel (x only)
__device__ __forceinline__ void split_bf(float f, short& hi, short& lo) {
    union { float f; unsigned u; } v; v.f = f;
    hi = (short)(v.u >> 16);
    union { unsigned u; float f; } h; h.u = v.u & 0xffff0000u;
    float r = f - h.f;
    union { float f; unsigned u; } w; w.f = r;
    lo = (short)(w.u >> 16);
}

__device__ __forceinline__ bf16x8 ldwfrag(const float* __restrict__ W,
                                          int n, int stride, int k0, int kmax) {
    bf16x8 r;
    #pragma unroll
    for (int j = 0; j < 8; ++j) {
        int k = k0 + j;
        float f = (k < kmax) ? W[n * stride + k] : 0.0f;
        r[j] = f2bf_rne(f);
    }
    return r;
}

#define MF(A, B, C) __builtin_amdgcn_mfma_f32_16x16x32_bf16(A, B, C, 0, 0, 0)
#define LKW() asm volatile("s_waitcnt lgkmcnt(0)" ::: "memory")

// One timestep. T: timestep; ROFF/BOFF/WOFF: compile-time ring byte offsets
// (own-read slot (T-1)&3, below-read slot T&3, write slot T&3).
#define STEP(T, ROFF, BOFF, WOFF) do {                                       \
    const int t_ = (T);                                                      \
    /* ---- spin-poll dependencies (flags monotonic, wg-uniform) ---- */     \
    {                                                                        \
        const int nO = t_ - 1;                                               \
        int spins = 0;                                                       \
        for (;;) {                                                           \
            bool ok = (vfl[wg4 + 0] >= nO) & (vfl[wg4 + 1] >= nO)            \
                    & (vfl[wg4 + 2] >= nO) & (vfl[wg4 + 3] >= nO);           \
            if (wg > 0) {                                                    \
                const int nB = t_;                                           \
                ok = ok & (vfl[wg4 - 4] >= nB) & (vfl[wg4 - 3] >= nB)        \
                        & (vfl[wg4 - 2] >= nB) & (vfl[wg4 - 1] >= nB);       \
            }                                                                \
            if (wg < 2) {                                                    \
                const int nA = t_ - 3;                                       \
                ok = ok & (vfl[wg4 + 4] >= nA) & (vfl[wg4 + 5] >= nA)        \
                        & (vfl[wg4 + 6] >= nA) & (vfl[wg4 + 7] >= nA);       \
            }                                                                \
            if (ok) break;                                                   \
            if (++spins > 100000) break;   /* bail: bug -> bad absmax */     \
        }                                                                    \
    }                                                                        \
    if (xmask) {   /* split prefetched x(t) into frags */                    \
        _Pragma("unroll")                                                    \
        for (int jj = 0; jj < In; ++jj) {                                    \
            short h_, l_; split_bf(xr[jj], h_, l_);                          \
            xhi[jj] = h_; xlo[jj] = l_;                                      \
        }                                                                    \
    }                                                                        \
    if (lreal) {   /* exec-masked frag loads: real rows only */              \
        oh0 = *(const bf16x8*)(roB + (ROFF));                                \
        oh1 = *(const bf16x8*)(roB + (ROFF) + 64);                           \
        if (wg > 0) {                                                        \
            bh0 = *(const bf16x8*)(rbB + (BOFF));                            \
            bh1 = *(const bf16x8*)(rbB + (BOFF) + 64);                       \
        }                                                                    \
    }                                                                        \
    f32x4 acc[4];                                                            \
    __builtin_amdgcn_s_setprio(1);                                           \
    _Pragma("unroll")                                                        \
    for (int gi = 0; gi < 4; ++gi)                                           \
        acc[gi] = MF(oh0, WH[gi][0], bsv[gi]);   /* bias as C */             \
    _Pragma("unroll")                                                        \
    for (int gi = 0; gi < 4; ++gi)                                           \
        acc[gi] = MF(oh1, WH[gi][1], acc[gi]);                               \
    if (wg == 0) {                     /* input: x(t), hi+lo */              \
        _Pragma("unroll")                                                    \
        for (int gi = 0; gi < 4; ++gi)                                       \
            acc[gi] = MF(xhi, WI[gi][0], acc[gi]);                           \
        _Pragma("unroll")                                                    \
        for (int gi = 0; gi < 4; ++gi)                                       \
            acc[gi] = MF(xlo, WI[gi][0], acc[gi]);                           \
    } else {                           /* input: h_below(t), hi-only */      \
        _Pragma("unroll")                                                    \
        for (int gi = 0; gi < 4; ++gi)                                       \
            acc[gi] = MF(bh0, WI[gi][0], acc[gi]);                           \
        _Pragma("unroll")                                                    \
        for (int gi = 0; gi < 4; ++gi)                                       \
            acc[gi] = MF(bh1, WI[gi][1], acc[gi]);                           \
    }                                                                        \
    __builtin_amdgcn_s_setprio(0);                                           \
    if (xmask && t_ + 1 < Tt) {        /* prefetch x(t+1) */                 \
        _Pragma("unroll")                                                    \
        for (int jj = 0; jj < In; ++jj)                                      \
            xr[jj] = x[xbase + (size_t)(t_ + 1) * In + jj];                  \
    }                                                                        \
    /* combine, j=0 only: output (b=kg, u=ub+col), all 64 lanes real */      \
    {                                                                        \
        float ei = __expf(-acc[0][0]);                                       \
        float ef = __expf(-acc[1][0]);                                       \
        float eg = __expf(-2.0f * acc[2][0]);                                \
        float eo = __expf(-acc[3][0]);                                       \
        float ig = (1.0f - eg) *                                             \
                   __builtin_amdgcn_rcpf((1.0f + ei) * (1.0f + eg));         \
        float fv = __builtin_amdgcn_rcpf(1.0f + ef);                         \
        float cn = fmaf(fv, c0, ig);                                         \
        c0 = cn;                                                             \
        float ov = __builtin_amdgcn_rcpf(1.0f + eo);                         \
        float hn = ov * tanhc(cn);                                           \
        unsigned pk_;                                                        \
        asm("v_cvt_pk_bf16_f32 %0, %1, %2" : "=v"(pk_) : "v"(hn), "v"(hn));  \
        *(short*)(wrB + (WOFF)) = (short)pk_;                                \
        if (wg == 2) h2f[kg][ub + col] = hn;   /* fp32 sidecar for FC */     \
    }                                                                        \
    LKW();                              /* h-write visible in LDS */         \
    if (l == 0) vfl[wg4 + w4] = t_;     /* publish progress (after LKW) */   \
} while (0)

__global__ __launch_bounds__(NT, 2) void lstm3_mfma(
    const float* __restrict__ x,
    const float* __restrict__ w_ih0, const float* __restrict__ w_hh0,
    const float* __restrict__ b_ih0, const float* __restrict__ b_hh0,
    const float* __restrict__ w_ih1, const float* __restrict__ w_hh1,
    const float* __restrict__ b_ih1, const float* __restrict__ b_hh1,
    const float* __restrict__ w_ih2, const float* __restrict__ w_hh2,
    const float* __restrict__ b_ih2, const float* __restrict__ b_hh2,
    const float* __restrict__ w_fc,  const float* __restrict__ b_fc,
    float* __restrict__ out)
{
    // [slot PB x4 | layer LB | row RB_] ring h buffer (32 KB)
    __shared__ short hb[NS][PB / 2];
    __shared__ float h2f[TBr][Hh];            // fp32 h2 sidecar (1 KB)
    __shared__ alignas(16) int wflag[3][4];   // per-wave progress flags

    const int tid = threadIdx.x;
    const int l   = tid & 63;
    const int wid = tid >> 6;        // 0..11
    const int wg  = wid >> 2;        // layer group 0..2
    const int w4  = wid & 3;         // wave within layer
    const int wg4 = wg * 4;          // flag index base
    const int ub  = w4 * 16;         // unit base
    const int col = l & 15;          // A-row / B-col index
    const int kg  = l >> 4;          // k-group 0..3
    const int b0  = blockIdx.x * TBr;
    const bool lreal = ((col & 3) == 0);   // lane's A-row is a real batch row

    volatile int* vfl = (volatile int*)wflag;

    // ---- zero all ring slots (h(t<0)=0) + init flags ----
    for (int i = tid; i < NS * PB / 4; i += NT) ((int*)hb)[i] = 0;
    if (tid < 12) ((int*)wflag)[tid] = -1;

    // ---- per-layer weight selection ----
    const float* whh = (wg == 0) ? w_hh0 : (wg == 1) ? w_hh1 : w_hh2;
    const float* wih = (wg == 0) ? w_ih0 : (wg == 1) ? w_ih1 : w_ih2;
    const float* bih = (wg == 0) ? b_ih0 : (wg == 1) ? b_ih1 : b_ih2;
    const float* bhh = (wg == 0) ? b_hh0 : (wg == 1) ? b_hh1 : b_hh2;

    // ---- weights -> register fragments (once); bias pre-splat as C ----
    bf16x8 WH[4][2], WI[4][2];
    f32x4  bsv[4];
    #pragma unroll
    for (int gi = 0; gi < 4; ++gi) {
        int n = gi * 64 + ub + col;
        float bs_ = bih[n] + bhh[n];
        bsv[gi] = (f32x4){bs_, bs_, bs_, bs_};
        #pragma unroll
        for (int kt = 0; kt < 2; ++kt) {
            WH[gi][kt] = ldwfrag(whh, n, Hh, kt * 32 + kg * 8, Hh);
            if (wg == 0) {
                WI[gi][kt] = (kt == 0) ? ldwfrag(wih, n, In, kg * 8, In)
                                       : ldwfrag(wih, n, In, 64, 0);
            } else {
                WI[gi][kt] = ldwfrag(wih, n, Hh, kt * 32 + kg * 8, Hh);
            }
        }
    }

    // ---- loop-invariant slot-0 LDS base pointers (+ kg*16 k-slice) ----
    char* hbB = (char*)hb;
    const int lbelow = (wg > 0) ? (wg - 1) : 0;
    const char* roB = hbB + wg     * LB + col * RB_ + kg * 16;   // own read
    const char* rbB = hbB + lbelow * LB + col * RB_ + kg * 16;   // below read
    // write: real batch b=kg lives at tile row 4*kg (j=0 slot of kg)
    char* wrB = hbB + wg * LB + (kg * 4) * RB_ + (ub + col) * 2;

    // ---- x prefetch: only lanes whose A-row is real (col%4==0) ----
    const bool xmask = (wg == 0) && (kg == 0) && lreal;
    const size_t xbase = (size_t)(b0 + (col >> 2)) * Tt * In;
    float xr[5] = {0.f, 0.f, 0.f, 0.f, 0.f};
    // persistent fragments: dead lanes keep zeros forever (= LDS zeros)
    bf16x8 xhi, xlo, oh0, oh1, bh0, bh1;
    #pragma unroll
    for (int j = 0; j < 8; ++j) {
        xhi[j] = 0; xlo[j] = 0; oh0[j] = 0; oh1[j] = 0; bh0[j] = 0; bh1[j] = 0;
    }
    if (xmask) {
        #pragma unroll
        for (int j = 0; j < In; ++j) xr[j] = x[xbase + j];
    }

    float c0 = 0.f;   // cell state for (b=kg, u=ub+col)

    __syncthreads();   // zero-init + flags visible (the ONLY loop barrier)

    // ---- decoupled main loop: each wg runs its own t=0..255 ----
    // 4x unroll makes ring offsets compile-time: own-read slot (t-1)&3,
    // below-read/write slot t&3.
    #pragma unroll 1
    for (int t4 = 0; t4 < Tt; t4 += 4) {
        STEP(t4 + 0, 3 * PB, 0,      0     );
        STEP(t4 + 1, 0,      PB,     PB    );
        STEP(t4 + 2, PB,     2 * PB, 2 * PB);
        STEP(t4 + 3, 2 * PB, 3 * PB, 3 * PB);
    }

    __syncthreads();   // all wgs done; h2f final

    // ---- final FC on h2(T-1) from the fp32 sidecar ----
    if (tid < TBr) {
        const int b = tid;
        float accf = b_fc[0];
        #pragma unroll 1
        for (int u = 0; u < Hh; ++u)
            accf = fmaf(h2f[b][u], w_fc[u], accf);
        out[b0 + b] = accf;
    }
}

extern "C" void kernel_launch(void* const* d_in, const int* in_sizes, int n_in,
                              void* d_out, int out_size, void* d_ws, size_t ws_size,
                              hipStream_t stream) {
    const float* x     = (const float*)d_in[0];
    const float* w_ih0 = (const float*)d_in[1];
    const float* w_hh0 = (const float*)d_in[2];
    const float* b_ih0 = (const float*)d_in[3];
    const float* b_hh0 = (const float*)d_in[4];
    const float* w_ih1 = (const float*)d_in[5];
    const float* w_hh1 = (const float*)d_in[6];
    const float* b_ih1 = (const float*)d_in[7];
    const float* b_hh1 = (const float*)d_in[8];
    const float* w_ih2 = (const float*)d_in[9];
    const float* w_hh2 = (const float*)d_in[10];
    const float* b_ih2 = (const float*)d_in[11];
    const float* b_hh2 = (const float*)d_in[12];
    const float* w_fc  = (const float*)d_in[13];
    const float* b_fc  = (const float*)d_in[14];
    float* out = (float*)d_out;

    lstm3_mfma<<<NB, NT, 0, stream>>>(x,
        w_ih0, w_hh0, b_ih0, b_hh0,
        w_ih1, w_hh1, b_ih1, b_hh1,
        w_ih2, w_hh2, b_ih2, b_hh2,
        w_fc, b_fc, out);
}